// Round 21
// baseline (181.321 us; speedup 1.0000x reference)
//
#include <hip/hip_runtime.h>

#define B 2
#define S 2048
#define D 768
#define H 12
#define DH 64
#define TOPK 512
#define NROW (B*S)   // 4096

typedef __attribute__((ext_vector_type(8))) short bf16x8;
typedef __attribute__((ext_vector_type(8))) ushort u16x8;
typedef __attribute__((ext_vector_type(4))) float f32x4;

#define QKVSZ ((size_t)B*H*S*DH)   // 3,145,728
#define WSZC  ((size_t)D*D)        // 589,824

// ---- bf16 split helpers (hi = RNE bf16 of x, lo = RNE bf16 of residual) ----
__device__ __forceinline__ ushort bf16_hi(float x) {
  union { float f; unsigned u; } v; v.f = x;
  unsigned r = v.u + 0x7fffu + ((v.u >> 16) & 1u);
  return (ushort)(r >> 16);
}
__device__ __forceinline__ float bf16_tof(ushort h) {
  union { float f; unsigned u; } v; v.u = ((unsigned)h) << 16; return v.f;
}
__device__ __forceinline__ void bf16_split(float x, ushort& h, ushort& l) {
  h = bf16_hi(x);
  l = bf16_hi(x - bf16_tof(h));
}

// ---- async global->LDS 16B (DMA; LDS dest = wave-uniform base + lane*16) --
__device__ __forceinline__ void gload_lds16(const ushort* g, ushort* l) {
  __builtin_amdgcn_global_load_lds(
      (const __attribute__((address_space(1))) void*)g,
      (__attribute__((address_space(3))) void*)l, 16, 0, 0);
}

// ---------------------------------------------------------------------------
// Fused split pass: z = 0..3 -> Wq/Wk/Wv/Wo slabs; z = 4..6 -> q/k/v slabs.
// ---------------------------------------------------------------------------
__global__ __launch_bounds__(256) void splitall_kernel(
    const float* __restrict__ q, const float* __restrict__ k,
    const float* __restrict__ v,
    const float* __restrict__ w0, const float* __restrict__ w1,
    const float* __restrict__ w2, const float* __restrict__ w3,
    ushort* __restrict__ Wbase, ushort* __restrict__ X3h,
    ushort* __restrict__ X3l, int nW8, int nX8) {
  int z = blockIdx.z;
  const float* src; ushort* dh; ushort* dl; int n8;
  if (z < 4) {
    src = (z == 0) ? w0 : (z == 1) ? w1 : (z == 2) ? w2 : w3;
    dh = Wbase + (size_t)z * 2u * WSZC; dl = dh + WSZC; n8 = nW8;
  } else {
    int y = z - 4;
    src = (y == 0) ? q : (y == 1) ? k : v;
    dh = X3h + (size_t)y * QKVSZ; dl = X3l + (size_t)y * QKVSZ; n8 = nX8;
  }
  int i = blockIdx.x*256 + threadIdx.x;
  if (i >= n8) return;
  float vv[8];
  *(float4*)&vv[0] = ((const float4*)src)[i*2];
  *(float4*)&vv[4] = ((const float4*)src)[i*2+1];
  ushort hh[8], ll[8];
#pragma unroll
  for (int kk = 0; kk < 8; ++kk) bf16_split(vv[kk], hh[kk], ll[kk]);
  ((u16x8*)dh)[i] = *(u16x8*)&hh[0];
  ((u16x8*)dl)[i] = *(u16x8*)&ll[0];
}

// ---------------------------------------------------------------------------
// projmf v7 (R17/R19-proven, 52us QKV): 64x128 tile, single-buffer DMA
// staging, source-swizzled linear LDS, 48KB -> 3 blocks/CU. K-proj (z=1)
// 4-term; Q/V/O 3-term. At the 2-barrier structure ceiling (~950 TF) —
// 8-phase escape is documented NULL at sub-256^2 tiles (m232), and 256^2
// tiles give only 48 blocks at N=768. Frozen.
// ---------------------------------------------------------------------------
template<int PATH>
__global__ __launch_bounds__(256) void projmf2_kernel(
    const ushort* __restrict__ Ah_base, const ushort* __restrict__ Al_base,
    const ushort* __restrict__ Wbase,
    const float* __restrict__ bq, const float* __restrict__ bk,
    const float* __restrict__ bv, const float* __restrict__ bo,
    float* __restrict__ Kout, float* __restrict__ Vout,
    ushort* __restrict__ Qh, ushort* __restrict__ Ql,
    ushort* __restrict__ Kbh, ushort* __restrict__ Kbl,
    float* __restrict__ Oout) {
  __shared__ __align__(16) ushort Ash[64*64],  Asl[64*64];
  __shared__ __align__(16) ushort Wsh[128*64], Wsl[128*64];
  int tid = threadIdx.x;
  int w = tid >> 6, lane = tid & 63;
  int lr = lane & 15, lg = lane >> 4;
  int z = (PATH == 0) ? blockIdx.z : 3;
  const bool four = (PATH == 0) && (z == 1);
  const ushort* Ah = Ah_base + (PATH == 0 ? (size_t)z * QKVSZ : 0);
  const ushort* Al = Al_base + (PATH == 0 ? (size_t)z * QKVSZ : 0);
  const ushort* Wh = Wbase + (size_t)z * 2u * WSZC;
  const ushort* Wl = Wh + WSZC;
  const float* bias = (PATH == 1) ? bo : (z == 0 ? bq : (z == 1 ? bk : bv));
  float scale = (PATH == 0 && z == 0) ? 0.125f : 1.0f;
  int n0 = blockIdx.x*64, m0 = blockIdx.y*128;
  int wr0 = (w >> 1)*32;
  int wc0 = (w & 1)*64;
  int rsub = lane >> 3;
  int dcol = (lane & 7) * 8;
  int scol = dcol ^ ((rsub & 7) << 3);
  int drowA = w*16 + rsub;
  int drowW = w*32 + rsub;
  f32x4 acc[2][4] = {};
  for (int kt = 0; kt < 12; ++kt) {
    int k0 = kt*64;
    size_t gA = (size_t)(n0 + drowA)*768 + k0 + scol;
    size_t gW = (size_t)(m0 + drowW)*768 + k0 + scol;
    gload_lds16(Ah + gA,          Ash + w*1024);
    gload_lds16(Ah + gA + 8*768,  Ash + w*1024 + 512);
    gload_lds16(Al + gA,          Asl + w*1024);
    gload_lds16(Al + gA + 8*768,  Asl + w*1024 + 512);
#pragma unroll
    for (int t = 0; t < 4; ++t) {
      gload_lds16(Wh + gW + (size_t)t*8*768, Wsh + w*2048 + t*512);
      gload_lds16(Wl + gW + (size_t)t*8*768, Wsl + w*2048 + t*512);
    }
    __syncthreads();
#pragma unroll
    for (int ks = 0; ks < 2; ++ks) {
      int co = ks*32 + lg*8;
      bf16x8 fah[2], fal[2], fwh[4], fwl[4];
#pragma unroll
      for (int i = 0; i < 2; ++i) {
        int ar = wr0 + 16*i + lr;
        int ca = co ^ ((ar & 7) << 3);
        fah[i] = *(const bf16x8*)&Ash[ar*64 + ca];
        fal[i] = *(const bf16x8*)&Asl[ar*64 + ca];
      }
#pragma unroll
      for (int j = 0; j < 4; ++j) {
        int wr2 = wc0 + 16*j + lr;
        int cw = co ^ ((wr2 & 7) << 3);
        fwh[j] = *(const bf16x8*)&Wsh[wr2*64 + cw];
        fwl[j] = *(const bf16x8*)&Wsl[wr2*64 + cw];
      }
#pragma unroll
      for (int i = 0; i < 2; ++i)
#pragma unroll
        for (int j = 0; j < 4; ++j) {
          acc[i][j] = __builtin_amdgcn_mfma_f32_16x16x32_bf16(fah[i], fwh[j], acc[i][j], 0, 0, 0);
          acc[i][j] = __builtin_amdgcn_mfma_f32_16x16x32_bf16(fah[i], fwl[j], acc[i][j], 0, 0, 0);
          acc[i][j] = __builtin_amdgcn_mfma_f32_16x16x32_bf16(fal[i], fwh[j], acc[i][j], 0, 0, 0);
          if (four)
            acc[i][j] = __builtin_amdgcn_mfma_f32_16x16x32_bf16(fal[i], fwl[j], acc[i][j], 0, 0, 0);
        }
    }
    __syncthreads();
  }
#pragma unroll
  for (int i = 0; i < 2; ++i)
#pragma unroll
    for (int j = 0; j < 4; ++j) {
      int m = m0 + wc0 + 16*j + lr;
      float bvv = bias[m];
#pragma unroll
      for (int r = 0; r < 4; ++r) {
        int n = n0 + wr0 + 16*i + lg*4 + r;
        float val = (acc[i][j][r] + bvv) * scale;
        if (PATH == 1) {
          Oout[(size_t)n*D + m] = val;
        } else {
          int b = n >> 11, s = n & 2047, hh2 = m >> 6, dh2 = m & 63;
          size_t o = (((size_t)b*H + hh2)*S + s)*DH + dh2;
          if (z == 0) {
            ushort vh, vl; bf16_split(val, vh, vl);
            Qh[o] = vh; Ql[o] = vl;
          } else if (z == 1) {
            Kout[o] = val;
            if (b == 0) {
              ushort vh, vl; bf16_split(val, vh, vl);
              Kbh[o] = vh; Kbl[o] = vl;
            }
          } else {
            Vout[o] = val;
          }
        }
      }
    }
}

// ---------------------------------------------------------------------------
// Leverage stage A1: per-head partial KtK over 128-row chunks (batch 0 only)
// ---------------------------------------------------------------------------
__global__ __launch_bounds__(256) void levA1_kernel(
    const float* __restrict__ Kmat, float* __restrict__ partials) {
  int h = blockIdx.x, blk = blockIdx.y;
  __shared__ __align__(16) float ktile[128*64];
  int tid = threadIdx.x;
  const float* Kh = Kmat + ((size_t)h*S + (size_t)blk*128)*DH;
#pragma unroll
  for (int r = 0; r < 32; ++r) { int e = tid + 256*r; ktile[e] = Kh[e]; }
  __syncthreads();
  int j4 = tid & 15;
  float accf[4][4] = {};
  for (int ss = 0; ss < 128; ++ss) {
    float4 kj = ((const float4*)(ktile + ss*64))[j4];
#pragma unroll
    for (int r = 0; r < 4; ++r) {
      int i = (tid >> 4) + 16*r;
      float ki = ktile[ss*64 + i];
      accf[r][0] += ki*kj.x; accf[r][1] += ki*kj.y;
      accf[r][2] += ki*kj.z; accf[r][3] += ki*kj.w;
    }
  }
  size_t base = ((size_t)h*16 + blk)*4096;
#pragma unroll
  for (int r = 0; r < 4; ++r) {
    int i = (tid >> 4) + 16*r;
#pragma unroll
    for (int c = 0; c < 4; ++c)
      partials[base + (size_t)i*64 + j4*4 + c] = accf[r][c];
  }
}

// ---------------------------------------------------------------------------
// Leverage stage A0-reduce: fp64 sum of the 16 partials + damping.
// ---------------------------------------------------------------------------
__global__ __launch_bounds__(256) void levA0_kernel(
    const float* __restrict__ partials, float* __restrict__ KtK) {
  int g = blockIdx.x*256 + threadIdx.x;        // 0 .. H*4096-1
  int h = g >> 12, e = g & 4095;
  const float* pb = partials + (size_t)h*65536 + e;
  double t = 0.0;
#pragma unroll
  for (int p = 0; p < 16; ++p) t += (double)pb[(size_t)p*4096];
  if ((e >> 6) == (e & 63)) t += 1e-6;
  KtK[g] = (float)t;
}

// ---------------------------------------------------------------------------
// Newton-iteration inverse via MFMA. One block (256 thr, 4 waves) per head.
// ---------------------------------------------------------------------------
__global__ __launch_bounds__(256) void newton_inv_kernel(
    const float* __restrict__ KtK, float* __restrict__ invOut,
    ushort* __restrict__ invH, ushort* __restrict__ invL) {
  const int SF = 68;
  const int SB = 72;
  __shared__ float Xf[64*SF];
  __shared__ float Uf[64*SF];
  __shared__ __align__(16) ushort Ah[64*SB], Al[64*SB];
  __shared__ __align__(16) ushort Xh[64*SB], Xl[64*SB];
  __shared__ __align__(16) ushort Th[64*SB], Tl[64*SB];
  __shared__ float rsum[64];
  __shared__ float csh;
  int h = blockIdx.x, tid = threadIdx.x;
  int w = tid >> 6, lane = tid & 63;
  int lr = lane & 15, lg = lane >> 4;
  int r = tid >> 2, qq = tid & 3;

  float s = 0.f;
  {
    const float* src = KtK + (size_t)h*4096 + (size_t)r*64 + qq*16;
#pragma unroll
    for (int i = 0; i < 16; ++i) {
      float a = src[i];
      s += fabsf(a);
      ushort hh, ll; bf16_split(a, hh, ll);
      Ah[r*SB + qq*16 + i] = hh; Al[r*SB + qq*16 + i] = ll;
    }
    s += __shfl_xor(s, 1);
    s += __shfl_xor(s, 2);
    if (qq == 0) rsum[r] = s;
  }
  __syncthreads();
  if (tid < 64) {
    float m = rsum[tid];
#pragma unroll
    for (int o = 32; o; o >>= 1) m = fmaxf(m, __shfl_xor(m, o));
    if (tid == 0) csh = 1.0f / m;
  }
  __syncthreads();
  float c = csh;
#pragma unroll
  for (int i = 0; i < 16; ++i) {
    int e = qq*16 + i;
    float x0 = (e == r) ? c : 0.0f;
    Xf[r*SF + e] = x0;
    ushort hh, ll; bf16_split(x0, hh, ll);
    Xh[r*SB + e] = hh; Xl[r*SB + e] = ll;
  }
  __syncthreads();

  int n0 = (w >> 1)*32, m0 = (w & 1)*32;
  for (int it = 0; it < 12; ++it) {
    // P1: T' = X * A^T
    {
      f32x4 acc[2][2] = {};
#pragma unroll
      for (int ks = 0; ks < 2; ++ks) {
        bf16x8 pah[2], pal[2], pbh[2], pbl[2];
#pragma unroll
        for (int i = 0; i < 2; ++i) {
          int ao = (n0 + 16*i + lr)*SB + ks*32 + lg*8;
          pah[i] = *(const bf16x8*)&Xh[ao]; pal[i] = *(const bf16x8*)&Xl[ao];
          int bo2 = (m0 + 16*i + lr)*SB + ks*32 + lg*8;
          pbh[i] = *(const bf16x8*)&Ah[bo2]; pbl[i] = *(const bf16x8*)&Al[bo2];
        }
#pragma unroll
        for (int i = 0; i < 2; ++i)
#pragma unroll
          for (int j = 0; j < 2; ++j) {
            acc[i][j] = __builtin_amdgcn_mfma_f32_16x16x32_bf16(pah[i], pbh[j], acc[i][j], 0, 0, 0);
            acc[i][j] = __builtin_amdgcn_mfma_f32_16x16x32_bf16(pah[i], pbl[j], acc[i][j], 0, 0, 0);
            acc[i][j] = __builtin_amdgcn_mfma_f32_16x16x32_bf16(pal[i], pbh[j], acc[i][j], 0, 0, 0);
            acc[i][j] = __builtin_amdgcn_mfma_f32_16x16x32_bf16(pal[i], pbl[j], acc[i][j], 0, 0, 0);
          }
      }
#pragma unroll
      for (int i = 0; i < 2; ++i)
#pragma unroll
        for (int j = 0; j < 2; ++j)
#pragma unroll
          for (int rr = 0; rr < 4; ++rr) {
            int n = n0 + 16*i + lg*4 + rr, m = m0 + 16*j + lr;
            ushort hh, ll; bf16_split(acc[i][j][rr], hh, ll);
            Th[n*SB + m] = hh; Tl[n*SB + m] = ll;
          }
    }
    __syncthreads();
    // P2: U = X * T'^T
    {
      f32x4 acc[2][2] = {};
#pragma unroll
      for (int ks = 0; ks < 2; ++ks) {
        bf16x8 pah[2], pal[2], pbh[2], pbl[2];
#pragma unroll
        for (int i = 0; i < 2; ++i) {
          int ao = (n0 + 16*i + lr)*SB + ks*32 + lg*8;
          pah[i] = *(const bf16x8*)&Xh[ao]; pal[i] = *(const bf16x8*)&Xl[ao];
          int bo2 = (m0 + 16*i + lr)*SB + ks*32 + lg*8;
          pbh[i] = *(const bf16x8*)&Th[bo2]; pbl[i] = *(const bf16x8*)&Tl[bo2];
        }
#pragma unroll
        for (int i = 0; i < 2; ++i)
#pragma unroll
          for (int j = 0; j < 2; ++j) {
            acc[i][j] = __builtin_amdgcn_mfma_f32_16x16x32_bf16(pah[i], pbh[j], acc[i][j], 0, 0, 0);
            acc[i][j] = __builtin_amdgcn_mfma_f32_16x16x32_bf16(pah[i], pbl[j], acc[i][j], 0, 0, 0);
            acc[i][j] = __builtin_amdgcn_mfma_f32_16x16x32_bf16(pal[i], pbh[j], acc[i][j], 0, 0, 0);
            acc[i][j] = __builtin_amdgcn_mfma_f32_16x16x32_bf16(pal[i], pbl[j], acc[i][j], 0, 0, 0);
          }
      }
#pragma unroll
      for (int i = 0; i < 2; ++i)
#pragma unroll
        for (int j = 0; j < 2; ++j)
#pragma unroll
          for (int rr = 0; rr < 4; ++rr) {
            int n = n0 + 16*i + lg*4 + rr, m = m0 + 16*j + lr;
            Uf[n*SF + m] = acc[i][j][rr];
          }
    }
    __syncthreads();
    // P3: X' = 2X - 0.5(U + U^T)
#pragma unroll
    for (int i = 0; i < 2; ++i)
#pragma unroll
      for (int j = 0; j < 2; ++j)
#pragma unroll
        for (int rr = 0; rr < 4; ++rr) {
          int n = n0 + 16*i + lg*4 + rr, m = m0 + 16*j + lr;
          float u = 0.5f*(Uf[n*SF + m] + Uf[m*SF + n]);
          float x = 2.0f*Xf[n*SF + m] - u;
          Xf[n*SF + m] = x;
          ushort hh, ll; bf16_split(x, hh, ll);
          Xh[n*SB + m] = hh; Xl[n*SB + m] = ll;
        }
    __syncthreads();
  }

#pragma unroll
  for (int i = 0; i < 16; ++i) {
    float x = Xf[r*SF + qq*16 + i];
    size_t o = (size_t)h*4096 + (size_t)r*64 + qq*16 + i;
    invOut[o] = x;
    ushort hh, ll; bf16_split(x, hh, ll);
    invH[o] = hh; invL[o] = ll;
  }
}

// ---------------------------------------------------------------------------
// Leverage stage B via MFMA: T = K @ inv (inv symmetric), lev = rowsum(T*K).
// ---------------------------------------------------------------------------
__global__ __launch_bounds__(256) void levB_kernel(
    const float* __restrict__ Kmat,
    const ushort* __restrict__ Kbh, const ushort* __restrict__ Kbl,
    const ushort* __restrict__ invH, const ushort* __restrict__ invL,
    float* __restrict__ lev) {
  int h = blockIdx.y;
  int tid = threadIdx.x;
  int w = tid >> 6, lane = tid & 63;
  int lr = lane & 15, lg = lane >> 4;
  int qbase = blockIdx.x*64 + w*16;
  f32x4 sacc[4] = {};
#pragma unroll
  for (int ks = 0; ks < 2; ++ks) {
    size_t ko = ((size_t)h*S + qbase + lr)*DH + ks*32 + lg*8;
    bf16x8 kh = *(const bf16x8*)(Kbh + ko);
    bf16x8 kl = *(const bf16x8*)(Kbl + ko);
#pragma unroll
    for (int f = 0; f < 4; ++f) {
      size_t io = (size_t)h*4096 + (size_t)(16*f + lr)*64 + ks*32 + lg*8;
      bf16x8 ih = *(const bf16x8*)(invH + io);
      bf16x8 il = *(const bf16x8*)(invL + io);
      sacc[f] = __builtin_amdgcn_mfma_f32_16x16x32_bf16(kh, ih, sacc[f], 0, 0, 0);
      sacc[f] = __builtin_amdgcn_mfma_f32_16x16x32_bf16(kh, il, sacc[f], 0, 0, 0);
      sacc[f] = __builtin_amdgcn_mfma_f32_16x16x32_bf16(kl, ih, sacc[f], 0, 0, 0);
      sacc[f] = __builtin_amdgcn_mfma_f32_16x16x32_bf16(kl, il, sacc[f], 0, 0, 0);
    }
  }
  float zc[4] = {};
#pragma unroll
  for (int f = 0; f < 4; ++f)
#pragma unroll
    for (int r = 0; r < 4; ++r) {
      float kv = Kmat[((size_t)h*S + qbase + lg*4 + r)*DH + 16*f + lr];
      zc[r] = fmaf(sacc[f][r], kv, zc[r]);
    }
#pragma unroll
  for (int r = 0; r < 4; ++r) {
    float t = zc[r];
    t += __shfl_xor(t, 1);
    t += __shfl_xor(t, 2);
    t += __shfl_xor(t, 4);
    t += __shfl_xor(t, 8);
    if (lr == 0) lev[(size_t)h*S + qbase + lg*4 + r] = t;
  }
}

// ---------------------------------------------------------------------------
// Top-k via RADIX SELECT (set identical to (value desc, index asc) sort).
// ---------------------------------------------------------------------------
__global__ __launch_bounds__(256) void topk_kernel(
    const float* __restrict__ lev, int* __restrict__ idx_list) {
  __shared__ unsigned hist[256];
  __shared__ unsigned wsum[4];
  __shared__ unsigned selS[2];   // [0]=new remaining, [1]=selected byte
  int h = blockIdx.x, tid = threadIdx.x;
  int lane = tid & 63, wid = tid >> 6;
  unsigned k[8];
  {
    const float* src = lev + (size_t)h*S + tid*8;
    float v[8];
    *(float4*)&v[0] = ((const float4*)src)[0];
    *(float4*)&v[4] = ((const float4*)src)[1];
#pragma unroll
    for (int i = 0; i < 8; ++i) {
      unsigned u = __float_as_uint(v[i]);
      k[i] = (u & 0x80000000u) ? ~u : (u | 0x80000000u);
    }
  }
  unsigned prefix = 0, remaining = TOPK;
  for (int pass = 0; pass < 4; ++pass) {
    int shift = 24 - pass*8;
    unsigned maskHi = (pass == 0) ? 0u : (0xFFFFFFFFu << (shift + 8));
    hist[tid] = 0;
    __syncthreads();
#pragma unroll
    for (int i = 0; i < 8; ++i)
      if ((k[i] & maskHi) == prefix)
        atomicAdd(&hist[(k[i] >> shift) & 0xFF], 1u);
    __syncthreads();
    unsigned own = hist[255 - tid];
    unsigned x = own;
#pragma unroll
    for (int o = 1; o < 64; o <<= 1) {
      unsigned n = __shfl_up(x, o);
      if (lane >= o) x += n;
    }
    if (lane == 63) wsum[wid] = x;
    __syncthreads();
    unsigned wofs = 0;
#pragma unroll
    for (int ww = 0; ww < 3; ++ww) if (wid > ww) wofs += wsum[ww];
    unsigned inc = x + wofs;
    unsigned exc = inc - own;
    if (inc >= remaining && exc < remaining) {
      selS[0] = remaining - exc;
      selS[1] = (unsigned)(255 - tid);
    }
    __syncthreads();
    prefix |= selS[1] << shift;
    remaining = selS[0];
    __syncthreads();
  }
  unsigned T = prefix;
  unsigned needEq = remaining;
  unsigned g[8], e[8];
  unsigned gcnt = 0, ecnt = 0;
#pragma unroll
  for (int i = 0; i < 8; ++i) {
    g[i] = (k[i] > T) ? 1u : 0u;
    e[i] = (k[i] == T) ? 1u : 0u;
    gcnt += g[i]; ecnt += e[i];
  }
  unsigned p = (gcnt << 16) | ecnt;
  unsigned x = p;
#pragma unroll
  for (int o = 1; o < 64; o <<= 1) {
    unsigned n = __shfl_up(x, o);
    if (lane >= o) x += n;
  }
  if (lane == 63) wsum[wid] = x;
  __syncthreads();
  unsigned wofs = 0;
#pragma unroll
  for (int ww = 0; ww < 3; ++ww) if (wid > ww) wofs += wsum[ww];
  unsigned excl = x - p + wofs;
  unsigned gBefore = excl >> 16, eBefore = excl & 0xFFFFu;
#pragma unroll
  for (int i = 0; i < 8; ++i) {
    bool keep = g[i] || (e[i] && eBefore < needEq);
    if (keep) {
      unsigned pos = gBefore + (eBefore < needEq ? eBefore : needEq);
      idx_list[h*TOPK + pos] = tid*8 + i;
    }
    gBefore += g[i];
    eBefore += e[i];
  }
}

// ---------------------------------------------------------------------------
// Gather kept K/V rows -> bf16 split buffers.
// KCh/KCl: [bh][512][64]; VCth/VCtl: [bh][64][512] (transposed)
// ---------------------------------------------------------------------------
__global__ __launch_bounds__(256) void gather_kernel(
    const float* __restrict__ Kmat, const float* __restrict__ Vmat,
    const int* __restrict__ idx_list,
    ushort* __restrict__ KCh, ushort* __restrict__ KCl,
    ushort* __restrict__ VCth, ushort* __restrict__ VCtl) {
  int bh = blockIdx.x;        // 0..23
  int kc = blockIdx.y;        // 0..7
  int h = bh % H;
  __shared__ float vt[64][65];
  int tid = threadIdx.x;
  int kk = tid >> 2;           // key within chunk (0..63)
  int dq = (tid & 3) * 16;     // dh base (0,16,32,48)
  int j = kc*64 + kk;
  int srow = idx_list[h*TOPK + j];
  const float* kr = Kmat + ((size_t)bh*S + srow)*DH + dq;
  const float* vr = Vmat + ((size_t)bh*S + srow)*DH + dq;
  ushort hh[16], ll[16];
#pragma unroll
  for (int i = 0; i < 16; ++i) bf16_split(kr[i], hh[i], ll[i]);
  size_t kbase = ((size_t)bh*TOPK + j)*DH + dq;
  *(u16x8*)(KCh + kbase)     = *(u16x8*)&hh[0];
  *(u16x8*)(KCh + kbase + 8) = *(u16x8*)&hh[8];
  *(u16x8*)(KCl + kbase)     = *(u16x8*)&ll[0];
  *(u16x8*)(KCl + kbase + 8) = *(u16x8*)&ll[8];
#pragma unroll
  for (int i = 0; i < 16; ++i) vt[kk][dq + i] = vr[i];
  __syncthreads();
  int d  = tid >> 2;           // dh row (0..63)
  int kq = (tid & 3) * 16;     // key base within chunk
#pragma unroll
  for (int i = 0; i < 16; ++i) bf16_split(vt[kq + i][d], hh[i], ll[i]);
  size_t vbase = ((size_t)bh*DH + d)*TOPK + kc*64 + kq;
  *(u16x8*)(VCth + vbase)     = *(u16x8*)&hh[0];
  *(u16x8*)(VCth + vbase + 8) = *(u16x8*)&hh[8];
  *(u16x8*)(VCtl + vbase)     = *(u16x8*)&ll[0];
  *(u16x8*)(VCtl + vbase + 8) = *(u16x8*)&ll[8];
}

// ---------------------------------------------------------------------------
// MFMA attention v3: 2 q-tiles per block (QT2). Each block stages its K/V
// chunk ONCE and runs two compute phases against it — staging ops and K/V
// L2 traffic halve vs R20's 1-tile blocks; per-q-row arithmetic (fragments,
// order) is BITWISE unchanged (canary absmax 4.882812e-4). SQ tiles are
// reused across the two phases (same-wave write->read->rewrite, program-
// order safe). p-loop fully unrolled -> all acc indices compile-time.
// Grid 384 = 8 xcd x 3 bh x 16 q-pairs (XCD-grouped swizzle).
// ---------------------------------------------------------------------------
__global__ __launch_bounds__(256) void attn_kernel(
    const ushort* __restrict__ Qh_g, const ushort* __restrict__ Ql_g,
    const ushort* __restrict__ KCh, const ushort* __restrict__ KCl,
    const ushort* __restrict__ VCth, const ushort* __restrict__ VCtl,
    ushort* __restrict__ CTXh, ushort* __restrict__ CTXl) {
  __shared__ __align__(16) ushort Kt_h[64*64], Kt_l[64*64];
  __shared__ __align__(16) ushort Vt_h[64*64], Vt_l[64*64];
  __shared__ __align__(16) ushort SQh[4][16][88];
  __shared__ __align__(16) ushort SQl[4][16][88];
  int tid = threadIdx.x;
  int w = tid >> 6;
  int lane = tid & 63;
  int lr = lane & 15, lg = lane >> 4;
  int bid = blockIdx.x;                 // 384 blocks
  int xcd = bid & 7, jj = bid >> 3;     // jj 0..47
  int bh = xcd*3 + (jj >> 4);           // 3 bh per xcd
  int qp = jj & 15;                     // q-pair tile
  int b = bh / H, h = bh % H;
  int qbase0 = qp*128 + w*16;           // phase 0 rows
  int qbase1 = qbase0 + 64;             // phase 1 rows

  // Q fragments for both phases, loaded once
  bf16x8 qh[2][2], ql[2][2];
#pragma unroll
  for (int p = 0; p < 2; ++p) {
    int qb = (p == 0) ? qbase0 : qbase1;
#pragma unroll
    for (int ks = 0; ks < 2; ++ks) {
      size_t qo = ((size_t)bh*S + qb + lr)*DH + ks*32 + lg*8;
      qh[p][ks] = *(const bf16x8*)(Qh_g + qo);
      ql[p][ks] = *(const bf16x8*)(Ql_g + qo);
    }
  }

  f32x4 pacc[2][4] = {};
  float z_acc[2][4] = {};
  int srow = tid >> 2;
  int sseg = (tid & 3) * 16;
  int swz = (srow & 7) << 3;
  int sc0 = sseg ^ swz;
  int sc1 = (sseg + 8) ^ swz;

  for (int c = 0; c < 8; ++c) {
    int keybase = c*64;
    {
      size_t kg = ((size_t)bh*TOPK + keybase + srow)*DH + sseg;
      size_t vg = ((size_t)bh*DH + srow)*TOPK + keybase + sseg;
      u16x8 a0 = *(const u16x8*)(KCh + kg);
      u16x8 a1 = *(const u16x8*)(KCh + kg + 8);
      u16x8 b0 = *(const u16x8*)(KCl + kg);
      u16x8 b1 = *(const u16x8*)(KCl + kg + 8);
      u16x8 c0 = *(const u16x8*)(VCth + vg);
      u16x8 c1 = *(const u16x8*)(VCth + vg + 8);
      u16x8 d0 = *(const u16x8*)(VCtl + vg);
      u16x8 d1 = *(const u16x8*)(VCtl + vg + 8);
      int lb = srow*64;
      *(u16x8*)&Kt_h[lb + sc0] = a0; *(u16x8*)&Kt_h[lb + sc1] = a1;
      *(u16x8*)&Kt_l[lb + sc0] = b0; *(u16x8*)&Kt_l[lb + sc1] = b1;
      *(u16x8*)&Vt_h[lb + sc0] = c0; *(u16x8*)&Vt_h[lb + sc1] = c1;
      *(u16x8*)&Vt_l[lb + sc0] = d0; *(u16x8*)&Vt_l[lb + sc1] = d1;
    }
    __syncthreads();
#pragma unroll
    for (int p = 0; p < 2; ++p) {
      f32x4 sacc[4] = {};
#pragma unroll
      for (int ks = 0; ks < 2; ++ks) {
        int co = ks*32 + lg*8;
        int ca = co ^ ((lr & 7) << 3);
#pragma unroll
        for (int f = 0; f < 4; ++f) {
          int ko = (16*f + lr)*64 + ca;
          bf16x8 kh = *(const bf16x8*)&Kt_h[ko];
          bf16x8 kl = *(const bf16x8*)&Kt_l[ko];
          sacc[f] = __builtin_amdgcn_mfma_f32_16x16x32_bf16(qh[p][ks], kh, sacc[f], 0, 0, 0);
          sacc[f] = __builtin_amdgcn_mfma_f32_16x16x32_bf16(qh[p][ks], kl, sacc[f], 0, 0, 0);
          sacc[f] = __builtin_amdgcn_mfma_f32_16x16x32_bf16(ql[p][ks], kh, sacc[f], 0, 0, 0);
        }
      }
      float zc[4] = {};
#pragma unroll
      for (int f = 0; f < 4; ++f) {
#pragma unroll
        for (int r = 0; r < 4; ++r) {
          float s = sacc[f][r];
          float sq = s*s;
          zc[r] += sq;
          ushort hh, lo2; bf16_split(sq, hh, lo2);
          SQh[w][lg*4 + r][16*f + lr] = hh;
          SQl[w][lg*4 + r][16*f + lr] = lo2;
        }
      }
#pragma unroll
      for (int r = 0; r < 4; ++r) {
        float t = zc[r];
        t += __shfl_xor(t, 1);
        t += __shfl_xor(t, 2);
        t += __shfl_xor(t, 4);
        t += __shfl_xor(t, 8);
        z_acc[p][r] += t;
      }
#pragma unroll
      for (int ks = 0; ks < 2; ++ks) {
        int co = ks*32 + lg*8;
        int ca = co ^ ((lr & 7) << 3);
        bf16x8 ah = *(const bf16x8*)&SQh[w][lr][ks*32 + lg*8];
        bf16x8 al = *(const bf16x8*)&SQl[w][lr][ks*32 + lg*8];
#pragma unroll
        for (int f = 0; f < 4; ++f) {
          int vo = (16*f + lr)*64 + ca;
          bf16x8 vh = *(const bf16x8*)&Vt_h[vo];
          bf16x8 vl = *(const bf16x8*)&Vt_l[vo];
          pacc[p][f] = __builtin_amdgcn_mfma_f32_16x16x32_bf16(ah, vh, pacc[p][f], 0, 0, 0);
          pacc[p][f] = __builtin_amdgcn_mfma_f32_16x16x32_bf16(ah, vl, pacc[p][f], 0, 0, 0);
          pacc[p][f] = __builtin_amdgcn_mfma_f32_16x16x32_bf16(al, vh, pacc[p][f], 0, 0, 0);
        }
      }
    }
    __syncthreads();
  }

#pragma unroll
  for (int p = 0; p < 2; ++p) {
    int qb = (p == 0) ? qbase0 : qbase1;
    float zi[4];
#pragma unroll
    for (int r = 0; r < 4; ++r) zi[r] = 1.0f / (z_acc[p][r] + 1e-12f);
#pragma unroll
    for (int f = 0; f < 4; ++f) {
#pragma unroll
      for (int r = 0; r < 4; ++r) {
        int q = lg*4 + r;
        float val = pacc[p][f][r] * zi[r];
        ushort hh, lo2; bf16_split(val, hh, lo2);
        size_t o = ((size_t)b*S + qb + q)*D + h*DH + 16*f + lr;
        CTXh[o] = hh; CTXl[o] = lo2;
      }
    }
  }
}

// ---------------------------------------------------------------------------
extern "C" void kernel_launch(void* const* d_in, const int* in_sizes, int n_in,
                              void* d_out, int out_size, void* d_ws, size_t ws_size,
                              hipStream_t stream) {
  const float* query = (const float*)d_in[0];
  const float* key   = (const float*)d_in[1];
  const float* value = (const float*)d_in[2];
  const float* Wq = (const float*)d_in[3];
  const float* bq = (const float*)d_in[4];
  const float* Wk = (const float*)d_in[5];
  const float* bk = (const float*)d_in[6];
  const float* Wv = (const float*)d_in[7];
  const float* bv = (const float*)d_in[8];
  const float* Wo = (const float*)d_in[9];
  const float* bo = (const float*)d_in[10];
  float* out = (float*)d_out;

  const size_t QKV = QKVSZ;
  const size_t WSZ = WSZC;
  const size_t KB0 = (size_t)H*S*DH;          // 1,572,864 (batch-0 K)
  ushort* X3h = (ushort*)d_ws;                // [3][QKV] input splits
  ushort* X3l = X3h + 3*QKV;
  ushort* Wqh = X3l + 3*QKV;                  // 8 contiguous W slabs
  ushort* Qh  = Wqh + 8*WSZ;
  ushort* Ql  = Qh + QKV;
  float*  Kws = (float*)(Ql + QKV);
  float*  Vws = Kws + QKV;
  float*  partials = Vws + QKV;               // 786,432
  float*  ktkWs = partials + (size_t)H*16*4096;
  float*  invWs = ktkWs + (size_t)H*4096;
  float*  levWs = invWs + (size_t)H*4096;
  ushort* Xh  = (ushort*)(levWs + (size_t)H*S);   // ctx split (attn out)
  ushort* Xl  = Xh + QKV;
  ushort* KCh  = Xl + QKV;
  ushort* KCl  = KCh  + (size_t)B*H*TOPK*DH;
  ushort* VCth = KCl  + (size_t)B*H*TOPK*DH;
  ushort* VCtl = VCth + (size_t)B*H*TOPK*DH;
  ushort* Kbh  = VCtl + (size_t)B*H*TOPK*DH;  // batch-0 K split
  ushort* Kbl  = Kbh + KB0;
  ushort* invH = Kbl + KB0;
  ushort* invL = invH + (size_t)H*4096;
  int*   idxWs = (int*)(invL + (size_t)H*4096);

  const int nW8 = (int)(WSZ/8), nX8 = (int)(QKV/8);
  // fused weight+input split (z=0..3 weights, z=4..6 inputs)
  splitall_kernel<<<dim3(nX8/256, 1, 7), 256, 0, stream>>>(
      query, key, value, Wq, Wk, Wv, Wo, Wqh, X3h, X3l, nW8, nX8);

  // batched QKV projection (z=0 Q 3-term, z=1 K 4-term, z=2 V 3-term)
  projmf2_kernel<0><<<dim3(NROW/64, D/128, 3), 256, 0, stream>>>(
      X3h, X3l, Wqh, bq, bk, bv, bo,
      Kws, Vws, Qh, Ql, Kbh, Kbl, nullptr);

  levA1_kernel<<<dim3(H,16), 256, 0, stream>>>(Kws, partials);
  levA0_kernel<<<(H*4096)/256, 256, 0, stream>>>(partials, ktkWs);
  newton_inv_kernel<<<H, 256, 0, stream>>>(ktkWs, invWs, invH, invL);
  levB_kernel<<<dim3(S/64, H), 256, 0, stream>>>(Kws, Kbh, Kbl, invH, invL, levWs);
  topk_kernel<<<H, 256, 0, stream>>>(levWs, idxWs);

  gather_kernel<<<dim3(B*H, TOPK/64), 256, 0, stream>>>(
      Kws, Vws, idxWs, KCh, KCl, VCth, VCtl);

  // QT2 attention: 384 blocks (8 xcd x 3 bh x 16 q-pairs)
  attn_kernel<<<B*H*(S/128), 256, 0, stream>>>(Qh, Ql, KCh, KCl, VCth, VCtl, Xh, Xl);

  // output projection (PATH 1: A = ctx splits, W = Wo slab, 3-term)
  projmf2_kernel<1><<<dim3(NROW/64, D/128, 1), 256, 0, stream>>>(
      Xh, Xl, Wqh, bq, bk, bv, bo,
      nullptr, nullptr, nullptr, nullptr, nullptr, nullptr, out);
}

// Round 22
// 178.073 us; speedup vs baseline: 1.0182x; 1.0182x over previous
//
#include <hip/hip_runtime.h>

#define B 2
#define S 2048
#define D 768
#define H 12
#define DH 64
#define TOPK 512
#define NROW (B*S)   // 4096

typedef __attribute__((ext_vector_type(8))) short bf16x8;
typedef __attribute__((ext_vector_type(8))) ushort u16x8;
typedef __attribute__((ext_vector_type(4))) float f32x4;

#define QKVSZ ((size_t)B*H*S*DH)   // 3,145,728
#define WSZC  ((size_t)D*D)        // 589,824

// ---- bf16 split helpers (hi = RNE bf16 of x, lo = RNE bf16 of residual) ----
__device__ __forceinline__ ushort bf16_hi(float x) {
  union { float f; unsigned u; } v; v.f = x;
  unsigned r = v.u + 0x7fffu + ((v.u >> 16) & 1u);
  return (ushort)(r >> 16);
}
__device__ __forceinline__ float bf16_tof(ushort h) {
  union { float f; unsigned u; } v; v.u = ((unsigned)h) << 16; return v.f;
}
__device__ __forceinline__ void bf16_split(float x, ushort& h, ushort& l) {
  h = bf16_hi(x);
  l = bf16_hi(x - bf16_tof(h));
}

// ---- async global->LDS 16B (DMA; LDS dest = wave-uniform base + lane*16) --
__device__ __forceinline__ void gload_lds16(const ushort* g, ushort* l) {
  __builtin_amdgcn_global_load_lds(
      (const __attribute__((address_space(1))) void*)g,
      (__attribute__((address_space(3))) void*)l, 16, 0, 0);
}

// ---------------------------------------------------------------------------
// Fused split pass: z = 0..3 -> Wq/Wk/Wv/Wo slabs; z = 4..6 -> q/k/v slabs.
// ---------------------------------------------------------------------------
__global__ __launch_bounds__(256) void splitall_kernel(
    const float* __restrict__ q, const float* __restrict__ k,
    const float* __restrict__ v,
    const float* __restrict__ w0, const float* __restrict__ w1,
    const float* __restrict__ w2, const float* __restrict__ w3,
    ushort* __restrict__ Wbase, ushort* __restrict__ X3h,
    ushort* __restrict__ X3l, int nW8, int nX8) {
  int z = blockIdx.z;
  const float* src; ushort* dh; ushort* dl; int n8;
  if (z < 4) {
    src = (z == 0) ? w0 : (z == 1) ? w1 : (z == 2) ? w2 : w3;
    dh = Wbase + (size_t)z * 2u * WSZC; dl = dh + WSZC; n8 = nW8;
  } else {
    int y = z - 4;
    src = (y == 0) ? q : (y == 1) ? k : v;
    dh = X3h + (size_t)y * QKVSZ; dl = X3l + (size_t)y * QKVSZ; n8 = nX8;
  }
  int i = blockIdx.x*256 + threadIdx.x;
  if (i >= n8) return;
  float vv[8];
  *(float4*)&vv[0] = ((const float4*)src)[i*2];
  *(float4*)&vv[4] = ((const float4*)src)[i*2+1];
  ushort hh[8], ll[8];
#pragma unroll
  for (int kk = 0; kk < 8; ++kk) bf16_split(vv[kk], hh[kk], ll[kk]);
  ((u16x8*)dh)[i] = *(u16x8*)&hh[0];
  ((u16x8*)dl)[i] = *(u16x8*)&ll[0];
}

// ---------------------------------------------------------------------------
// projmf v7 (R17/R19-proven, 52us QKV): 64x128 tile, single-buffer DMA
// staging, source-swizzled linear LDS, 48KB -> 3 blocks/CU. K-proj (z=1)
// 4-term; Q/V/O 3-term. Frozen at the 2-barrier structure ceiling.
// ---------------------------------------------------------------------------
template<int PATH>
__global__ __launch_bounds__(256) void projmf2_kernel(
    const ushort* __restrict__ Ah_base, const ushort* __restrict__ Al_base,
    const ushort* __restrict__ Wbase,
    const float* __restrict__ bq, const float* __restrict__ bk,
    const float* __restrict__ bv, const float* __restrict__ bo,
    float* __restrict__ Kout, float* __restrict__ Vout,
    ushort* __restrict__ Qh, ushort* __restrict__ Ql,
    ushort* __restrict__ Kbh, ushort* __restrict__ Kbl,
    float* __restrict__ Oout) {
  __shared__ __align__(16) ushort Ash[64*64],  Asl[64*64];
  __shared__ __align__(16) ushort Wsh[128*64], Wsl[128*64];
  int tid = threadIdx.x;
  int w = tid >> 6, lane = tid & 63;
  int lr = lane & 15, lg = lane >> 4;
  int z = (PATH == 0) ? blockIdx.z : 3;
  const bool four = (PATH == 0) && (z == 1);
  const ushort* Ah = Ah_base + (PATH == 0 ? (size_t)z * QKVSZ : 0);
  const ushort* Al = Al_base + (PATH == 0 ? (size_t)z * QKVSZ : 0);
  const ushort* Wh = Wbase + (size_t)z * 2u * WSZC;
  const ushort* Wl = Wh + WSZC;
  const float* bias = (PATH == 1) ? bo : (z == 0 ? bq : (z == 1 ? bk : bv));
  float scale = (PATH == 0 && z == 0) ? 0.125f : 1.0f;
  int n0 = blockIdx.x*64, m0 = blockIdx.y*128;
  int wr0 = (w >> 1)*32;
  int wc0 = (w & 1)*64;
  int rsub = lane >> 3;
  int dcol = (lane & 7) * 8;
  int scol = dcol ^ ((rsub & 7) << 3);
  int drowA = w*16 + rsub;
  int drowW = w*32 + rsub;
  f32x4 acc[2][4] = {};
  for (int kt = 0; kt < 12; ++kt) {
    int k0 = kt*64;
    size_t gA = (size_t)(n0 + drowA)*768 + k0 + scol;
    size_t gW = (size_t)(m0 + drowW)*768 + k0 + scol;
    gload_lds16(Ah + gA,          Ash + w*1024);
    gload_lds16(Ah + gA + 8*768,  Ash + w*1024 + 512);
    gload_lds16(Al + gA,          Asl + w*1024);
    gload_lds16(Al + gA + 8*768,  Asl + w*1024 + 512);
#pragma unroll
    for (int t = 0; t < 4; ++t) {
      gload_lds16(Wh + gW + (size_t)t*8*768, Wsh + w*2048 + t*512);
      gload_lds16(Wl + gW + (size_t)t*8*768, Wsl + w*2048 + t*512);
    }
    __syncthreads();
#pragma unroll
    for (int ks = 0; ks < 2; ++ks) {
      int co = ks*32 + lg*8;
      bf16x8 fah[2], fal[2], fwh[4], fwl[4];
#pragma unroll
      for (int i = 0; i < 2; ++i) {
        int ar = wr0 + 16*i + lr;
        int ca = co ^ ((ar & 7) << 3);
        fah[i] = *(const bf16x8*)&Ash[ar*64 + ca];
        fal[i] = *(const bf16x8*)&Asl[ar*64 + ca];
      }
#pragma unroll
      for (int j = 0; j < 4; ++j) {
        int wr2 = wc0 + 16*j + lr;
        int cw = co ^ ((wr2 & 7) << 3);
        fwh[j] = *(const bf16x8*)&Wsh[wr2*64 + cw];
        fwl[j] = *(const bf16x8*)&Wsl[wr2*64 + cw];
      }
#pragma unroll
      for (int i = 0; i < 2; ++i)
#pragma unroll
        for (int j = 0; j < 4; ++j) {
          acc[i][j] = __builtin_amdgcn_mfma_f32_16x16x32_bf16(fah[i], fwh[j], acc[i][j], 0, 0, 0);
          acc[i][j] = __builtin_amdgcn_mfma_f32_16x16x32_bf16(fah[i], fwl[j], acc[i][j], 0, 0, 0);
          acc[i][j] = __builtin_amdgcn_mfma_f32_16x16x32_bf16(fal[i], fwh[j], acc[i][j], 0, 0, 0);
          if (four)
            acc[i][j] = __builtin_amdgcn_mfma_f32_16x16x32_bf16(fal[i], fwl[j], acc[i][j], 0, 0, 0);
        }
    }
    __syncthreads();
  }
#pragma unroll
  for (int i = 0; i < 2; ++i)
#pragma unroll
    for (int j = 0; j < 4; ++j) {
      int m = m0 + wc0 + 16*j + lr;
      float bvv = bias[m];
#pragma unroll
      for (int r = 0; r < 4; ++r) {
        int n = n0 + wr0 + 16*i + lg*4 + r;
        float val = (acc[i][j][r] + bvv) * scale;
        if (PATH == 1) {
          Oout[(size_t)n*D + m] = val;
        } else {
          int b = n >> 11, s = n & 2047, hh2 = m >> 6, dh2 = m & 63;
          size_t o = (((size_t)b*H + hh2)*S + s)*DH + dh2;
          if (z == 0) {
            ushort vh, vl; bf16_split(val, vh, vl);
            Qh[o] = vh; Ql[o] = vl;
          } else if (z == 1) {
            Kout[o] = val;
            if (b == 0) {
              ushort vh, vl; bf16_split(val, vh, vl);
              Kbh[o] = vh; Kbl[o] = vl;
            }
          } else {
            Vout[o] = val;
          }
        }
      }
    }
}

// ---------------------------------------------------------------------------
// Leverage stage A1: per-head partial KtK over 128-row chunks (batch 0 only)
// ---------------------------------------------------------------------------
__global__ __launch_bounds__(256) void levA1_kernel(
    const float* __restrict__ Kmat, float* __restrict__ partials) {
  int h = blockIdx.x, blk = blockIdx.y;
  __shared__ __align__(16) float ktile[128*64];
  int tid = threadIdx.x;
  const float* Kh = Kmat + ((size_t)h*S + (size_t)blk*128)*DH;
#pragma unroll
  for (int r = 0; r < 32; ++r) { int e = tid + 256*r; ktile[e] = Kh[e]; }
  __syncthreads();
  int j4 = tid & 15;
  float accf[4][4] = {};
  for (int ss = 0; ss < 128; ++ss) {
    float4 kj = ((const float4*)(ktile + ss*64))[j4];
#pragma unroll
    for (int r = 0; r < 4; ++r) {
      int i = (tid >> 4) + 16*r;
      float ki = ktile[ss*64 + i];
      accf[r][0] += ki*kj.x; accf[r][1] += ki*kj.y;
      accf[r][2] += ki*kj.z; accf[r][3] += ki*kj.w;
    }
  }
  size_t base = ((size_t)h*16 + blk)*4096;
#pragma unroll
  for (int r = 0; r < 4; ++r) {
    int i = (tid >> 4) + 16*r;
#pragma unroll
    for (int c = 0; c < 4; ++c)
      partials[base + (size_t)i*64 + j4*4 + c] = accf[r][c];
  }
}

// ---------------------------------------------------------------------------
// Leverage stage A0-reduce: fp64 sum of the 16 partials + damping.
// ---------------------------------------------------------------------------
__global__ __launch_bounds__(256) void levA0_kernel(
    const float* __restrict__ partials, float* __restrict__ KtK) {
  int g = blockIdx.x*256 + threadIdx.x;        // 0 .. H*4096-1
  int h = g >> 12, e = g & 4095;
  const float* pb = partials + (size_t)h*65536 + e;
  double t = 0.0;
#pragma unroll
  for (int p = 0; p < 16; ++p) t += (double)pb[(size_t)p*4096];
  if ((e >> 6) == (e & 63)) t += 1e-6;
  KtK[g] = (float)t;
}

// ---------------------------------------------------------------------------
// Newton-iteration inverse via MFMA. One block (256 thr, 4 waves) per head.
// ---------------------------------------------------------------------------
__global__ __launch_bounds__(256) void newton_inv_kernel(
    const float* __restrict__ KtK, float* __restrict__ invOut,
    ushort* __restrict__ invH, ushort* __restrict__ invL) {
  const int SF = 68;
  const int SB = 72;
  __shared__ float Xf[64*SF];
  __shared__ float Uf[64*SF];
  __shared__ __align__(16) ushort Ah[64*SB], Al[64*SB];
  __shared__ __align__(16) ushort Xh[64*SB], Xl[64*SB];
  __shared__ __align__(16) ushort Th[64*SB], Tl[64*SB];
  __shared__ float rsum[64];
  __shared__ float csh;
  int h = blockIdx.x, tid = threadIdx.x;
  int w = tid >> 6, lane = tid & 63;
  int lr = lane & 15, lg = lane >> 4;
  int r = tid >> 2, qq = tid & 3;

  float s = 0.f;
  {
    const float* src = KtK + (size_t)h*4096 + (size_t)r*64 + qq*16;
#pragma unroll
    for (int i = 0; i < 16; ++i) {
      float a = src[i];
      s += fabsf(a);
      ushort hh, ll; bf16_split(a, hh, ll);
      Ah[r*SB + qq*16 + i] = hh; Al[r*SB + qq*16 + i] = ll;
    }
    s += __shfl_xor(s, 1);
    s += __shfl_xor(s, 2);
    if (qq == 0) rsum[r] = s;
  }
  __syncthreads();
  if (tid < 64) {
    float m = rsum[tid];
#pragma unroll
    for (int o = 32; o; o >>= 1) m = fmaxf(m, __shfl_xor(m, o));
    if (tid == 0) csh = 1.0f / m;
  }
  __syncthreads();
  float c = csh;
#pragma unroll
  for (int i = 0; i < 16; ++i) {
    int e = qq*16 + i;
    float x0 = (e == r) ? c : 0.0f;
    Xf[r*SF + e] = x0;
    ushort hh, ll; bf16_split(x0, hh, ll);
    Xh[r*SB + e] = hh; Xl[r*SB + e] = ll;
  }
  __syncthreads();

  int n0 = (w >> 1)*32, m0 = (w & 1)*32;
  for (int it = 0; it < 12; ++it) {
    // P1: T' = X * A^T
    {
      f32x4 acc[2][2] = {};
#pragma unroll
      for (int ks = 0; ks < 2; ++ks) {
        bf16x8 pah[2], pal[2], pbh[2], pbl[2];
#pragma unroll
        for (int i = 0; i < 2; ++i) {
          int ao = (n0 + 16*i + lr)*SB + ks*32 + lg*8;
          pah[i] = *(const bf16x8*)&Xh[ao]; pal[i] = *(const bf16x8*)&Xl[ao];
          int bo2 = (m0 + 16*i + lr)*SB + ks*32 + lg*8;
          pbh[i] = *(const bf16x8*)&Ah[bo2]; pbl[i] = *(const bf16x8*)&Al[bo2];
        }
#pragma unroll
        for (int i = 0; i < 2; ++i)
#pragma unroll
          for (int j = 0; j < 2; ++j) {
            acc[i][j] = __builtin_amdgcn_mfma_f32_16x16x32_bf16(pah[i], pbh[j], acc[i][j], 0, 0, 0);
            acc[i][j] = __builtin_amdgcn_mfma_f32_16x16x32_bf16(pah[i], pbl[j], acc[i][j], 0, 0, 0);
            acc[i][j] = __builtin_amdgcn_mfma_f32_16x16x32_bf16(pal[i], pbh[j], acc[i][j], 0, 0, 0);
            acc[i][j] = __builtin_amdgcn_mfma_f32_16x16x32_bf16(pal[i], pbl[j], acc[i][j], 0, 0, 0);
          }
      }
#pragma unroll
      for (int i = 0; i < 2; ++i)
#pragma unroll
        for (int j = 0; j < 2; ++j)
#pragma unroll
          for (int rr = 0; rr < 4; ++rr) {
            int n = n0 + 16*i + lg*4 + rr, m = m0 + 16*j + lr;
            ushort hh, ll; bf16_split(acc[i][j][rr], hh, ll);
            Th[n*SB + m] = hh; Tl[n*SB + m] = ll;
          }
    }
    __syncthreads();
    // P2: U = X * T'^T
    {
      f32x4 acc[2][2] = {};
#pragma unroll
      for (int ks = 0; ks < 2; ++ks) {
        bf16x8 pah[2], pal[2], pbh[2], pbl[2];
#pragma unroll
        for (int i = 0; i < 2; ++i) {
          int ao = (n0 + 16*i + lr)*SB + ks*32 + lg*8;
          pah[i] = *(const bf16x8*)&Xh[ao]; pal[i] = *(const bf16x8*)&Xl[ao];
          int bo2 = (m0 + 16*i + lr)*SB + ks*32 + lg*8;
          pbh[i] = *(const bf16x8*)&Th[bo2]; pbl[i] = *(const bf16x8*)&Tl[bo2];
        }
#pragma unroll
        for (int i = 0; i < 2; ++i)
#pragma unroll
          for (int j = 0; j < 2; ++j) {
            acc[i][j] = __builtin_amdgcn_mfma_f32_16x16x32_bf16(pah[i], pbh[j], acc[i][j], 0, 0, 0);
            acc[i][j] = __builtin_amdgcn_mfma_f32_16x16x32_bf16(pah[i], pbl[j], acc[i][j], 0, 0, 0);
            acc[i][j] = __builtin_amdgcn_mfma_f32_16x16x32_bf16(pal[i], pbh[j], acc[i][j], 0, 0, 0);
            acc[i][j] = __builtin_amdgcn_mfma_f32_16x16x32_bf16(pal[i], pbl[j], acc[i][j], 0, 0, 0);
          }
      }
#pragma unroll
      for (int i = 0; i < 2; ++i)
#pragma unroll
        for (int j = 0; j < 2; ++j)
#pragma unroll
          for (int rr = 0; rr < 4; ++rr) {
            int n = n0 + 16*i + lg*4 + rr, m = m0 + 16*j + lr;
            Uf[n*SF + m] = acc[i][j][rr];
          }
    }
    __syncthreads();
    // P3: X' = 2X - 0.5(U + U^T)
#pragma unroll
    for (int i = 0; i < 2; ++i)
#pragma unroll
      for (int j = 0; j < 2; ++j)
#pragma unroll
        for (int rr = 0; rr < 4; ++rr) {
          int n = n0 + 16*i + lg*4 + rr, m = m0 + 16*j + lr;
          float u = 0.5f*(Uf[n*SF + m] + Uf[m*SF + n]);
          float x = 2.0f*Xf[n*SF + m] - u;
          Xf[n*SF + m] = x;
          ushort hh, ll; bf16_split(x, hh, ll);
          Xh[n*SB + m] = hh; Xl[n*SB + m] = ll;
        }
    __syncthreads();
  }

#pragma unroll
  for (int i = 0; i < 16; ++i) {
    float x = Xf[r*SF + qq*16 + i];
    size_t o = (size_t)h*4096 + (size_t)r*64 + qq*16 + i;
    invOut[o] = x;
    ushort hh, ll; bf16_split(x, hh, ll);
    invH[o] = hh; invL[o] = ll;
  }
}

// ---------------------------------------------------------------------------
// Leverage stage B via MFMA: T = K @ inv (inv symmetric), lev = rowsum(T*K).
// ---------------------------------------------------------------------------
__global__ __launch_bounds__(256) void levB_kernel(
    const float* __restrict__ Kmat,
    const ushort* __restrict__ Kbh, const ushort* __restrict__ Kbl,
    const ushort* __restrict__ invH, const ushort* __restrict__ invL,
    float* __restrict__ lev) {
  int h = blockIdx.y;
  int tid = threadIdx.x;
  int w = tid >> 6, lane = tid & 63;
  int lr = lane & 15, lg = lane >> 4;
  int qbase = blockIdx.x*64 + w*16;
  f32x4 sacc[4] = {};
#pragma unroll
  for (int ks = 0; ks < 2; ++ks) {
    size_t ko = ((size_t)h*S + qbase + lr)*DH + ks*32 + lg*8;
    bf16x8 kh = *(const bf16x8*)(Kbh + ko);
    bf16x8 kl = *(const bf16x8*)(Kbl + ko);
#pragma unroll
    for (int f = 0; f < 4; ++f) {
      size_t io = (size_t)h*4096 + (size_t)(16*f + lr)*64 + ks*32 + lg*8;
      bf16x8 ih = *(const bf16x8*)(invH + io);
      bf16x8 il = *(const bf16x8*)(invL + io);
      sacc[f] = __builtin_amdgcn_mfma_f32_16x16x32_bf16(kh, ih, sacc[f], 0, 0, 0);
      sacc[f] = __builtin_amdgcn_mfma_f32_16x16x32_bf16(kh, il, sacc[f], 0, 0, 0);
      sacc[f] = __builtin_amdgcn_mfma_f32_16x16x32_bf16(kl, ih, sacc[f], 0, 0, 0);
      sacc[f] = __builtin_amdgcn_mfma_f32_16x16x32_bf16(kl, il, sacc[f], 0, 0, 0);
    }
  }
  float zc[4] = {};
#pragma unroll
  for (int f = 0; f < 4; ++f)
#pragma unroll
    for (int r = 0; r < 4; ++r) {
      float kv = Kmat[((size_t)h*S + qbase + lg*4 + r)*DH + 16*f + lr];
      zc[r] = fmaf(sacc[f][r], kv, zc[r]);
    }
#pragma unroll
  for (int r = 0; r < 4; ++r) {
    float t = zc[r];
    t += __shfl_xor(t, 1);
    t += __shfl_xor(t, 2);
    t += __shfl_xor(t, 4);
    t += __shfl_xor(t, 8);
    if (lr == 0) lev[(size_t)h*S + qbase + lg*4 + r] = t;
  }
}

// ---------------------------------------------------------------------------
// Top-k via RADIX SELECT (set identical to (value desc, index asc) sort).
// ---------------------------------------------------------------------------
__global__ __launch_bounds__(256) void topk_kernel(
    const float* __restrict__ lev, int* __restrict__ idx_list) {
  __shared__ unsigned hist[256];
  __shared__ unsigned wsum[4];
  __shared__ unsigned selS[2];   // [0]=new remaining, [1]=selected byte
  int h = blockIdx.x, tid = threadIdx.x;
  int lane = tid & 63, wid = tid >> 6;
  unsigned k[8];
  {
    const float* src = lev + (size_t)h*S + tid*8;
    float v[8];
    *(float4*)&v[0] = ((const float4*)src)[0];
    *(float4*)&v[4] = ((const float4*)src)[1];
#pragma unroll
    for (int i = 0; i < 8; ++i) {
      unsigned u = __float_as_uint(v[i]);
      k[i] = (u & 0x80000000u) ? ~u : (u | 0x80000000u);
    }
  }
  unsigned prefix = 0, remaining = TOPK;
  for (int pass = 0; pass < 4; ++pass) {
    int shift = 24 - pass*8;
    unsigned maskHi = (pass == 0) ? 0u : (0xFFFFFFFFu << (shift + 8));
    hist[tid] = 0;
    __syncthreads();
#pragma unroll
    for (int i = 0; i < 8; ++i)
      if ((k[i] & maskHi) == prefix)
        atomicAdd(&hist[(k[i] >> shift) & 0xFF], 1u);
    __syncthreads();
    unsigned own = hist[255 - tid];
    unsigned x = own;
#pragma unroll
    for (int o = 1; o < 64; o <<= 1) {
      unsigned n = __shfl_up(x, o);
      if (lane >= o) x += n;
    }
    if (lane == 63) wsum[wid] = x;
    __syncthreads();
    unsigned wofs = 0;
#pragma unroll
    for (int ww = 0; ww < 3; ++ww) if (wid > ww) wofs += wsum[ww];
    unsigned inc = x + wofs;
    unsigned exc = inc - own;
    if (inc >= remaining && exc < remaining) {
      selS[0] = remaining - exc;
      selS[1] = (unsigned)(255 - tid);
    }
    __syncthreads();
    prefix |= selS[1] << shift;
    remaining = selS[0];
    __syncthreads();
  }
  unsigned T = prefix;
  unsigned needEq = remaining;
  unsigned g[8], e[8];
  unsigned gcnt = 0, ecnt = 0;
#pragma unroll
  for (int i = 0; i < 8; ++i) {
    g[i] = (k[i] > T) ? 1u : 0u;
    e[i] = (k[i] == T) ? 1u : 0u;
    gcnt += g[i]; ecnt += e[i];
  }
  unsigned p = (gcnt << 16) | ecnt;
  unsigned x = p;
#pragma unroll
  for (int o = 1; o < 64; o <<= 1) {
    unsigned n = __shfl_up(x, o);
    if (lane >= o) x += n;
  }
  if (lane == 63) wsum[wid] = x;
  __syncthreads();
  unsigned wofs = 0;
#pragma unroll
  for (int ww = 0; ww < 3; ++ww) if (wid > ww) wofs += wsum[ww];
  unsigned excl = x - p + wofs;
  unsigned gBefore = excl >> 16, eBefore = excl & 0xFFFFu;
#pragma unroll
  for (int i = 0; i < 8; ++i) {
    bool keep = g[i] || (e[i] && eBefore < needEq);
    if (keep) {
      unsigned pos = gBefore + (eBefore < needEq ? eBefore : needEq);
      idx_list[h*TOPK + pos] = tid*8 + i;
    }
    gBefore += g[i];
    eBefore += e[i];
  }
}

// ---------------------------------------------------------------------------
// Gather kept K/V rows -> bf16 split buffers.
// KCh/KCl: [bh][512][64]; VCth/VCtl: [bh][64][512] (transposed)
// ---------------------------------------------------------------------------
__global__ __launch_bounds__(256) void gather_kernel(
    const float* __restrict__ Kmat, const float* __restrict__ Vmat,
    const int* __restrict__ idx_list,
    ushort* __restrict__ KCh, ushort* __restrict__ KCl,
    ushort* __restrict__ VCth, ushort* __restrict__ VCtl) {
  int bh = blockIdx.x;        // 0..23
  int kc = blockIdx.y;        // 0..7
  int h = bh % H;
  __shared__ float vt[64][65];
  int tid = threadIdx.x;
  int kk = tid >> 2;           // key within chunk (0..63)
  int dq = (tid & 3) * 16;     // dh base (0,16,32,48)
  int j = kc*64 + kk;
  int srow = idx_list[h*TOPK + j];
  const float* kr = Kmat + ((size_t)bh*S + srow)*DH + dq;
  const float* vr = Vmat + ((size_t)bh*S + srow)*DH + dq;
  ushort hh[16], ll[16];
#pragma unroll
  for (int i = 0; i < 16; ++i) bf16_split(kr[i], hh[i], ll[i]);
  size_t kbase = ((size_t)bh*TOPK + j)*DH + dq;
  *(u16x8*)(KCh + kbase)     = *(u16x8*)&hh[0];
  *(u16x8*)(KCh + kbase + 8) = *(u16x8*)&hh[8];
  *(u16x8*)(KCl + kbase)     = *(u16x8*)&ll[0];
  *(u16x8*)(KCl + kbase + 8) = *(u16x8*)&ll[8];
#pragma unroll
  for (int i = 0; i < 16; ++i) vt[kk][dq + i] = vr[i];
  __syncthreads();
  int d  = tid >> 2;           // dh row (0..63)
  int kq = (tid & 3) * 16;     // key base within chunk
#pragma unroll
  for (int i = 0; i < 16; ++i) bf16_split(vt[kq + i][d], hh[i], ll[i]);
  size_t vbase = ((size_t)bh*DH + d)*TOPK + kc*64 + kq;
  *(u16x8*)(VCth + vbase)     = *(u16x8*)&hh[0];
  *(u16x8*)(VCth + vbase + 8) = *(u16x8*)&hh[8];
  *(u16x8*)(VCtl + vbase)     = *(u16x8*)&ll[0];
  *(u16x8*)(VCtl + vbase + 8) = *(u16x8*)&ll[8];
}

// ---------------------------------------------------------------------------
// MFMA attention (R20-proven): 1 q-tile/block, LDS-staged K/V with ST=64 +
// XOR swizzle (conflict-free), XCD-grouped swizzle, 768 blocks.
// ---------------------------------------------------------------------------
__global__ __launch_bounds__(256) void attn_kernel(
    const ushort* __restrict__ Qh_g, const ushort* __restrict__ Ql_g,
    const ushort* __restrict__ KCh, const ushort* __restrict__ KCl,
    const ushort* __restrict__ VCth, const ushort* __restrict__ VCtl,
    ushort* __restrict__ CTXh, ushort* __restrict__ CTXl) {
  __shared__ __align__(16) ushort Kt_h[64*64], Kt_l[64*64];
  __shared__ __align__(16) ushort Vt_h[64*64], Vt_l[64*64];
  __shared__ __align__(16) ushort SQh[4][16][88];
  __shared__ __align__(16) ushort SQl[4][16][88];
  int tid = threadIdx.x;
  int w = tid >> 6;
  int lane = tid & 63;
  int lr = lane & 15, lg = lane >> 4;
  int bid = blockIdx.x;
  int xcd = bid & 7, jj = bid >> 3;
  int bh = xcd*3 + (jj >> 5);
  int qt = jj & 31;
  int qbase = qt*64 + w*16;
  int b = bh / H, h = bh % H;

  bf16x8 qh[2], ql[2];
#pragma unroll
  for (int ks = 0; ks < 2; ++ks) {
    size_t qo = ((size_t)bh*S + qbase + lr)*DH + ks*32 + lg*8;
    qh[ks] = *(const bf16x8*)(Qh_g + qo);
    ql[ks] = *(const bf16x8*)(Ql_g + qo);
  }

  f32x4 pacc[4] = {};
  float z_acc[4] = {};
  int srow = tid >> 2;
  int sseg = (tid & 3) * 16;
  int swz = (srow & 7) << 3;
  int sc0 = sseg ^ swz;
  int sc1 = (sseg + 8) ^ swz;

  for (int c = 0; c < 8; ++c) {
    int keybase = c*64;
    {
      size_t kg = ((size_t)bh*TOPK + keybase + srow)*DH + sseg;
      size_t vg = ((size_t)bh*DH + srow)*TOPK + keybase + sseg;
      u16x8 a0 = *(const u16x8*)(KCh + kg);
      u16x8 a1 = *(const u16x8*)(KCh + kg + 8);
      u16x8 b0 = *(const u16x8*)(KCl + kg);
      u16x8 b1 = *(const u16x8*)(KCl + kg + 8);
      u16x8 c0 = *(const u16x8*)(VCth + vg);
      u16x8 c1 = *(const u16x8*)(VCth + vg + 8);
      u16x8 d0 = *(const u16x8*)(VCtl + vg);
      u16x8 d1 = *(const u16x8*)(VCtl + vg + 8);
      int lb = srow*64;
      *(u16x8*)&Kt_h[lb + sc0] = a0; *(u16x8*)&Kt_h[lb + sc1] = a1;
      *(u16x8*)&Kt_l[lb + sc0] = b0; *(u16x8*)&Kt_l[lb + sc1] = b1;
      *(u16x8*)&Vt_h[lb + sc0] = c0; *(u16x8*)&Vt_h[lb + sc1] = c1;
      *(u16x8*)&Vt_l[lb + sc0] = d0; *(u16x8*)&Vt_l[lb + sc1] = d1;
    }
    __syncthreads();
    f32x4 sacc[4] = {};
#pragma unroll
    for (int ks = 0; ks < 2; ++ks) {
      int co = ks*32 + lg*8;
      int ca = co ^ ((lr & 7) << 3);
#pragma unroll
      for (int f = 0; f < 4; ++f) {
        int ko = (16*f + lr)*64 + ca;
        bf16x8 kh = *(const bf16x8*)&Kt_h[ko];
        bf16x8 kl = *(const bf16x8*)&Kt_l[ko];
        sacc[f] = __builtin_amdgcn_mfma_f32_16x16x32_bf16(qh[ks], kh, sacc[f], 0, 0, 0);
        sacc[f] = __builtin_amdgcn_mfma_f32_16x16x32_bf16(qh[ks], kl, sacc[f], 0, 0, 0);
        sacc[f] = __builtin_amdgcn_mfma_f32_16x16x32_bf16(ql[ks], kh, sacc[f], 0, 0, 0);
      }
    }
    float zc[4] = {};
#pragma unroll
    for (int f = 0; f < 4; ++f) {
#pragma unroll
      for (int r = 0; r < 4; ++r) {
        float s = sacc[f][r];
        float sq = s*s;
        zc[r] += sq;
        ushort hh, lo2; bf16_split(sq, hh, lo2);
        SQh[w][lg*4 + r][16*f + lr] = hh;
        SQl[w][lg*4 + r][16*f + lr] = lo2;
      }
    }
#pragma unroll
    for (int r = 0; r < 4; ++r) {
      float t = zc[r];
      t += __shfl_xor(t, 1);
      t += __shfl_xor(t, 2);
      t += __shfl_xor(t, 4);
      t += __shfl_xor(t, 8);
      z_acc[r] += t;
    }
#pragma unroll
    for (int ks = 0; ks < 2; ++ks) {
      int co = ks*32 + lg*8;
      int ca = co ^ ((lr & 7) << 3);
      bf16x8 ah = *(const bf16x8*)&SQh[w][lr][ks*32 + lg*8];
      bf16x8 al = *(const bf16x8*)&SQl[w][lr][ks*32 + lg*8];
#pragma unroll
      for (int f = 0; f < 4; ++f) {
        int vo = (16*f + lr)*64 + ca;
        bf16x8 vh = *(const bf16x8*)&Vt_h[vo];
        bf16x8 vl = *(const bf16x8*)&Vt_l[vo];
        pacc[f] = __builtin_amdgcn_mfma_f32_16x16x32_bf16(ah, vh, pacc[f], 0, 0, 0);
        pacc[f] = __builtin_amdgcn_mfma_f32_16x16x32_bf16(ah, vl, pacc[f], 0, 0, 0);
        pacc[f] = __builtin_amdgcn_mfma_f32_16x16x32_bf16(al, vh, pacc[f], 0, 0, 0);
      }
    }
    __syncthreads();
  }

  float zi[4];
#pragma unroll
  for (int r = 0; r < 4; ++r) zi[r] = 1.0f / (z_acc[r] + 1e-12f);
#pragma unroll
  for (int f = 0; f < 4; ++f) {
#pragma unroll
    for (int r = 0; r < 4; ++r) {
      int q = lg*4 + r;
      float val = pacc[f][r] * zi[r];
      ushort hh, lo2; bf16_split(val, hh, lo2);
      size_t o = ((size_t)b*S + qbase + q)*D + h*DH + 16*f + lr;
      CTXh[o] = hh; CTXl[o] = lo2;
    }
  }
}

// ---------------------------------------------------------------------------
extern "C" void kernel_launch(void* const* d_in, const int* in_sizes, int n_in,
                              void* d_out, int out_size, void* d_ws, size_t ws_size,
                              hipStream_t stream) {
  const float* query = (const float*)d_in[0];
  const float* key   = (const float*)d_in[1];
  const float* value = (const float*)d_in[2];
  const float* Wq = (const float*)d_in[3];
  const float* bq = (const float*)d_in[4];
  const float* Wk = (const float*)d_in[5];
  const float* bk = (const float*)d_in[6];
  const float* Wv = (const float*)d_in[7];
  const float* bv = (const float*)d_in[8];
  const float* Wo = (const float*)d_in[9];
  const float* bo = (const float*)d_in[10];
  float* out = (float*)d_out;

  const size_t QKV = QKVSZ;
  const size_t WSZ = WSZC;
  const size_t KB0 = (size_t)H*S*DH;          // 1,572,864 (batch-0 K)
  ushort* X3h = (ushort*)d_ws;                // [3][QKV] input splits
  ushort* X3l = X3h + 3*QKV;
  ushort* Wqh = X3l + 3*QKV;                  // 8 contiguous W slabs
  ushort* Qh  = Wqh + 8*WSZ;
  ushort* Ql  = Qh + QKV;
  float*  Kws = (float*)(Ql + QKV);
  float*  Vws = Kws + QKV;
  float*  partials = Vws + QKV;               // 786,432
  float*  ktkWs = partials + (size_t)H*16*4096;
  float*  invWs = ktkWs + (size_t)H*4096;
  float*  levWs = invWs + (size_t)H*4096;
  ushort* Xh  = (ushort*)(levWs + (size_t)H*S);   // ctx split (attn out)
  ushort* Xl  = Xh + QKV;
  ushort* KCh  = Xl + QKV;
  ushort* KCl  = KCh  + (size_t)B*H*TOPK*DH;
  ushort* VCth = KCl  + (size_t)B*H*TOPK*DH;
  ushort* VCtl = VCth + (size_t)B*H*TOPK*DH;
  ushort* Kbh  = VCtl + (size_t)B*H*TOPK*DH;  // batch-0 K split
  ushort* Kbl  = Kbh + KB0;
  ushort* invH = Kbl + KB0;
  ushort* invL = invH + (size_t)H*4096;
  int*   idxWs = (int*)(invL + (size_t)H*4096);

  const int nW8 = (int)(WSZ/8), nX8 = (int)(QKV/8);
  // fused weight+input split (z=0..3 weights, z=4..6 inputs)
  splitall_kernel<<<dim3(nX8/256, 1, 7), 256, 0, stream>>>(
      query, key, value, Wq, Wk, Wv, Wo, Wqh, X3h, X3l, nW8, nX8);

  // batched QKV projection (z=0 Q 3-term, z=1 K 4-term, z=2 V 3-term)
  projmf2_kernel<0><<<dim3(NROW/64, D/128, 3), 256, 0, stream>>>(
      X3h, X3l, Wqh, bq, bk, bv, bo,
      Kws, Vws, Qh, Ql, Kbh, Kbl, nullptr);

  levA1_kernel<<<dim3(H,16), 256, 0, stream>>>(Kws, partials);
  levA0_kernel<<<(H*4096)/256, 256, 0, stream>>>(partials, ktkWs);
  newton_inv_kernel<<<H, 256, 0, stream>>>(ktkWs, invWs, invH, invL);
  levB_kernel<<<dim3(S/64, H), 256, 0, stream>>>(Kws, Kbh, Kbl, invH, invL, levWs);
  topk_kernel<<<H, 256, 0, stream>>>(levWs, idxWs);

  gather_kernel<<<dim3(B*H, TOPK/64), 256, 0, stream>>>(
      Kws, Vws, idxWs, KCh, KCl, VCth, VCtl);

  // R20 attention: 768 blocks (8 xcd x 3 bh x 32 q-tiles)
  attn_kernel<<<B*H*(S/64), 256, 0, stream>>>(Qh, Ql, KCh, KCl, VCth, VCtl, Xh, Xl);

  // output projection (PATH 1: A = ctx splits, W = Wo slab, 3-term)
  projmf2_kernel<1><<<dim3(NROW/64, D/128, 1), 256, 0, stream>>>(
      Xh, Xl, Wqh, bq, bk, bv, bo,
      nullptr, nullptr, nullptr, nullptr, nullptr, nullptr, out);
}